// Round 8
// baseline (1111.346 us; speedup 1.0000x reference)
//
#include <hip/hip_runtime.h>
#include <math.h>

typedef short short8v __attribute__((ext_vector_type(8)));
typedef float float4v __attribute__((ext_vector_type(4)));

// ---------------- workspace layout (bytes) ----------------
#define OFF_U     ((size_t)0)          // raw h2 (bias included, pre-squash): 512*1152*8*4 = 18,874,368
#define OFF_A     ((size_t)18874368)   // w2b bf16 10,616,832
#define OFF_W1T   ((size_t)29491200)   // w1t bf16 131,072
#define OFF_WT    ((size_t)30670848)   // Wt fp32 [n][o][e][d]: 5,898,240
#define OFF_SPART ((size_t)36569088)   // [16][512][160] f32 = 5,242,880
#define OFF_VSUM  ((size_t)41811968)   // 327,680 (end 42,139,648)

__device__ inline short f2bf(float f) {
  union { float f; unsigned u; } v; v.f = f;
  unsigned r = v.u + 0x7FFFu + ((v.u >> 16) & 1u);
  return (short)(r >> 16);
}

// ---------------- merged prep: w2b | w1t | Wt ----------------
// grid 7040: [0,1024) transpose w2->w2b, [1024,1280) w1->w1t, [1280,7040) W->Wt
__global__ __launch_bounds__(256) void prep_kernel(
    const float* __restrict__ w2, short* __restrict__ w2b,
    const float* __restrict__ w1, short* __restrict__ w1t,
    const float* __restrict__ W, float* __restrict__ Wt) {
  __shared__ short tl[81][66];
  int bx = blockIdx.x, t = threadIdx.x;
  if (bx < 1024) {
    int co = bx >> 2, ci0 = (bx & 3) * 64;
    for (int f = t; f < 64 * 81; f += 256) {
      int cip = f / 81, tap = f % 81;
      tl[tap][cip] = f2bf(w2[((size_t)co * 256 + ci0 + cip) * 81 + tap]);
    }
    __syncthreads();
    for (int f = t; f < 81 * 64; f += 256) {
      int tap = f >> 6, cip = f & 63;
      w2b[((size_t)tap * 256 + co) * 256 + ci0 + cip] = tl[tap][cip];
    }
  } else if (bx < 1280) {
    int co = bx - 1024;
    w1t[co * 256 + t] = (t < 243) ? f2bf(w1[(size_t)co * 243 + t]) : (short)0;
  } else {
    int idx = (bx - 1280) * 256 + t;
    if (idx < 1152 * 1280) {
      int n = idx / 1280, r = idx - n * 1280;
      int o = r >> 7, de = r & 127;
      int d = de >> 4, e = de & 15;
      Wt[(((size_t)n * 10 + o) * 16 + e) * 8 + d] = W[idx];
    }
  }
}

// ---------------- fused conv1(MFMA)+relu+conv2(MFMA) -> h2 raw ----------------
// 512 blocks (1 batch each, 2 blocks/CU), 256 threads (4 waves). Per ci-chunk of 32:
//   conv1: M=400 pos x N=32 co x K=256(pad 243), A gathered from x-LDS, B=w1t global
//   conv2: 81-tap implicit GEMM, M=48 (40 rows, 36 used), N=256, A=h1l LDS, B=w2b global
__global__ __launch_bounds__(256, 2) void conv_fused_kernel(
    const float* __restrict__ x, const short* __restrict__ w1t,
    const float* __restrict__ b1v, const short* __restrict__ w2b,
    const float* __restrict__ b2v, float* __restrict__ h2) {
  __shared__ short xsb[2352];        // 1 batch of x, bf16 (4.7 KB)
  __shared__ short h1l[400][40];     // h1 chunk bf16 [pos][32ci pad40] (32 KB)

  int b = blockIdx.x;
  int t = threadIdx.x;
  int lane = t & 63;
  int wv = t >> 6;
  int l15 = lane & 15, lq = lane >> 4;

  for (int i = t; i < 2352; i += 256) xsb[i] = f2bf(x[(size_t)b * 2352 + i]);

  float4v acc2[3][4];
#pragma unroll
  for (int mt = 0; mt < 3; mt++)
#pragma unroll
    for (int nt = 0; nt < 4; nt++) acc2[mt][nt] = (float4v){0.f, 0.f, 0.f, 0.f};

  int rowb[3];
#pragma unroll
  for (int mt = 0; mt < 3; mt++) {
    int s = mt * 16 + l15;
    if (s >= 36) s = 0;               // pad rows read row 0; discarded at store
    int sx = (s * 43) >> 8;           // s/6
    int sy = s - 6 * sx;
    rowb[mt] = sx * 40 + sy * 2;      // h1l row = rowb + kx*20 + ky
  }
  int co[4];
#pragma unroll
  for (int nt = 0; nt < 4; nt++) co[nt] = wv * 64 + nt * 16 + l15;

  int nmt = (wv == 0) ? 7 : 6;        // 25 M-tiles of conv1 split 7/6/6/6
  int px1[7], py1[7];
#pragma unroll
  for (int j = 0; j < 7; j++) {
    int pos = (wv + 4 * j) * 16 + l15;
    if (pos >= 400) pos = 0;
    px1[j] = (pos * 3277) >> 16;      // pos/20
    py1[j] = pos - 20 * px1[j];
  }

  for (int ch = 0; ch < 8; ch++) {
    int ci0 = ch * 32;
    __syncthreads();   // prev conv2 done with h1l (also covers xsb staging)

    // ======== conv1 phase (MFMA) ========
    float4v acc1[7][2];
#pragma unroll
    for (int j = 0; j < 7; j++)
#pragma unroll
      for (int nt = 0; nt < 2; nt++) acc1[j][nt] = (float4v){0.f, 0.f, 0.f, 0.f};
#pragma unroll 1
    for (int kk = 0; kk < 8; kk++) {
      int k0 = kk * 32 + lq * 8;
      int cin = (k0 * 810) >> 16;            // k0/81
      int rem = k0 - 81 * cin;
      int kx = (rem * 57) >> 9;              // rem/9
      int ky = rem - 9 * kx;
      int nv = 243 - k0; if (nv > 8) nv = 8; if (nv < 0) nv = 0;
      int n1 = 9 - ky; if (n1 > 8) n1 = 8;
      int d2 = (kx < 8) ? (28 - ky) : (560 - ky);
      short8v b1f[2];
#pragma unroll
      for (int nt = 0; nt < 2; nt++)
        b1f[nt] = *(const short8v*)(w1t + (size_t)(ci0 + nt * 16 + l15) * 256 + k0);
#pragma unroll
      for (int j = 0; j < 7; j++) {
        if (j < nmt) {
          int o1 = cin * 784 + (px1[j] + kx) * 28 + py1[j] + ky;
          short8v a;
#pragma unroll
          for (int jj = 0; jj < 8; jj++) {
            int idx = (jj < n1) ? (o1 + jj) : (o1 + d2 + jj - n1);
            if (jj >= nv) idx = 0;
            short vsh = xsb[idx];
            a[jj] = (jj < nv) ? vsh : (short)0;
          }
#pragma unroll
          for (int nt = 0; nt < 2; nt++)
            acc1[j][nt] = __builtin_amdgcn_mfma_f32_16x16x32_bf16(
                a, b1f[nt], acc1[j][nt], 0, 0, 0);
        }
      }
    }
    float bs[2];
#pragma unroll
    for (int nt = 0; nt < 2; nt++) bs[nt] = b1v[ci0 + nt * 16 + l15];
#pragma unroll
    for (int j = 0; j < 7; j++) {
      if (j < nmt) {
#pragma unroll
        for (int nt = 0; nt < 2; nt++) {
#pragma unroll
          for (int r = 0; r < 4; r++) {
            int pos = (wv + 4 * j) * 16 + lq * 4 + r;
            float h = acc1[j][nt][r] + bs[nt];
            h1l[pos][nt * 16 + l15] = f2bf(h > 0.f ? h : 0.f);
          }
        }
      }
    }
    __syncthreads();   // h1l ready

    // ======== conv2 phase: 81 taps, K=32, B-prefetch ring depth 3 ========
    short8v bA[4], bB[4], bC[4];
#pragma unroll
    for (int nt = 0; nt < 4; nt++) {
      const short* wb = w2b + (size_t)co[nt] * 256 + ci0 + lq * 8;
      bA[nt] = *(const short8v*)(wb);
      bB[nt] = *(const short8v*)(wb + 65536);
      bC[nt] = *(const short8v*)(wb + 2 * 65536);
    }
#pragma unroll 1
    for (int tg = 0; tg < 27; tg++) {
#pragma unroll
      for (int sl = 0; sl < 3; sl++) {
        int tap = tg * 3 + sl;
        int kx = (tap * 57) >> 9;
        int ky = tap - 9 * kx;
        int tf = tap + 3; if (tf > 80) tf = 80;
        short8v bcur[4];
#pragma unroll
        for (int nt = 0; nt < 4; nt++)
          bcur[nt] = (sl == 0) ? bA[nt] : (sl == 1) ? bB[nt] : bC[nt];
#pragma unroll
        for (int nt = 0; nt < 4; nt++) {
          short8v bn = *(const short8v*)(w2b + (size_t)tf * 65536 +
                                         (size_t)co[nt] * 256 + ci0 + lq * 8);
          if (sl == 0) bA[nt] = bn; else if (sl == 1) bB[nt] = bn; else bC[nt] = bn;
        }
        int dly = kx * 20 + ky;
#pragma unroll
        for (int mt = 0; mt < 3; mt++) {
          short8v af = *(const short8v*)&h1l[rowb[mt] + dly][lq * 8];
#pragma unroll
          for (int nt = 0; nt < 4; nt++)
            acc2[mt][nt] = __builtin_amdgcn_mfma_f32_16x16x32_bf16(
                af, bcur[nt], acc2[mt][nt], 0, 0, 0);
        }
      }
    }
  }

  // ---- epilogue: bias + store raw h2[b][co][s] (squash folded into readers) ----
#pragma unroll
  for (int nt = 0; nt < 4; nt++) {
    float bias = b2v[co[nt]];
#pragma unroll
    for (int mt = 0; mt < 3; mt++) {
#pragma unroll
      for (int r = 0; r < 4; r++) {
        int s = mt * 16 + lq * 4 + r;
        if (s < 36)
          h2[((size_t)b * 256 + co[nt]) * 36 + s] = acc2[mt][nt][r] + bias;
      }
    }
  }
}

// ---------------- fused routing pass: squash(u) + logits + softmax + s partials ----------------
// thread=(b,e): bl[o] via shfl_xor reduce over the 16 e-lanes; c in-register.
// vsum==nullptr -> iter 0 (uniform c; spart scaled 0.1 later in squash_v).
__global__ __launch_bounds__(256) void s_part_kernel(
    const float* __restrict__ h2u, const float* __restrict__ Wt,
    const float* __restrict__ vsum, float* __restrict__ spart) {
  int bt = blockIdx.x, nc = blockIdx.y;
  int t = threadIdx.x;
  int bq = t >> 4, e = t & 15;
  int b = bt * 16 + bq;
  float vsp[10];
  if (vsum != nullptr) {
#pragma unroll
    for (int o = 0; o < 10; o++) vsp[o] = vsum[(size_t)b * 160 + o * 16 + e];
  }
  float acc[10];
#pragma unroll
  for (int o = 0; o < 10; o++) acc[o] = 0.f;
  int n0 = nc * 72;
#pragma unroll 2
  for (int n = n0; n < n0 + 72; n++) {
    // load capsule (8 consecutive flat floats) and squash in-register
    const float4* up = (const float4*)(h2u + ((size_t)b * 1152 + n) * 8);
    float4 u0 = up[0], u1 = up[1];
    float sn = u0.x*u0.x + u0.y*u0.y + u0.z*u0.z + u0.w*u0.w +
               u1.x*u1.x + u1.y*u1.y + u1.z*u1.z + u1.w*u1.w;
    float sc = sn / (1.f + sn) / (sqrtf(sn) + 1e-6f);
    u0.x *= sc; u0.y *= sc; u0.z *= sc; u0.w *= sc;
    u1.x *= sc; u1.y *= sc; u1.z *= sc; u1.w *= sc;
    // uh[o] for this thread's e
    const float4* wp = (const float4*)(Wt + (size_t)n * 1280 + e * 8);
    float uh[10];
#pragma unroll
    for (int o = 0; o < 10; o++) {
      float4 w0 = wp[o * 32], w1 = wp[o * 32 + 1];
      uh[o] = u0.x * w0.x + u0.y * w0.y + u0.z * w0.z + u0.w * w0.w +
              u1.x * w1.x + u1.y * w1.y + u1.z * w1.z + u1.w * w1.w;
    }
    if (vsum != nullptr) {
      // bl[o] = sum_e uh[o][e]*vsum[b][o][e] via butterfly over the 16 e-lanes
      float bl[10];
#pragma unroll
      for (int o = 0; o < 10; o++) {
        float r = uh[o] * vsp[o];
        r += __shfl_xor(r, 1);
        r += __shfl_xor(r, 2);
        r += __shfl_xor(r, 4);
        r += __shfl_xor(r, 8);
        bl[o] = r;
      }
      float m = bl[0];
#pragma unroll
      for (int o = 1; o < 10; o++) m = fmaxf(m, bl[o]);
      float sum = 0.f;
#pragma unroll
      for (int o = 0; o < 10; o++) { bl[o] = __expf(bl[o] - m); sum += bl[o]; }
      float inv = 1.f / sum;
#pragma unroll
      for (int o = 0; o < 10; o++) acc[o] = fmaf(bl[o] * inv, uh[o], acc[o]);
    } else {
#pragma unroll
      for (int o = 0; o < 10; o++) acc[o] += uh[o];
    }
  }
  float* sp = spart + (size_t)nc * 81920 + (size_t)b * 160 + e;
#pragma unroll
  for (int o = 0; o < 10; o++) sp[o * 16] = acc[o];
}

// ---------------- v = squash(prescale * sum_parts); dst = v or dst += v ----------------
__global__ void squash_v_kernel(const float* __restrict__ spart,
                                float* __restrict__ dst, float prescale,
                                int accumulate) {
  int g = blockIdx.x * 256 + threadIdx.x;
  if (g >= 5120) return;
  float r[16];
#pragma unroll
  for (int e = 0; e < 16; e++) r[e] = 0.f;
#pragma unroll
  for (int p = 0; p < 16; p++) {
    const float4* sp = (const float4*)(spart + (size_t)p * 81920 + (size_t)g * 16);
#pragma unroll
    for (int q = 0; q < 4; q++) {
      float4 f4 = sp[q];
      r[4 * q] += f4.x; r[4 * q + 1] += f4.y; r[4 * q + 2] += f4.z; r[4 * q + 3] += f4.w;
    }
  }
  float sn = 0.f;
#pragma unroll
  for (int e = 0; e < 16; e++) { r[e] *= prescale; sn += r[e] * r[e]; }
  float scale = sn / (1.f + sn) / (sqrtf(sn) + 1e-6f);
  float* q = dst + (size_t)g * 16;
#pragma unroll
  for (int e = 0; e < 16; e++) {
    float val = r[e] * scale;
    q[e] = accumulate ? (q[e] + val) : val;
  }
}

extern "C" void kernel_launch(void* const* d_in, const int* in_sizes, int n_in,
                              void* d_out, int out_size, void* d_ws, size_t ws_size,
                              hipStream_t stream) {
  const float* x   = (const float*)d_in[0];
  const float* w1  = (const float*)d_in[1];
  const float* b1v = (const float*)d_in[2];
  const float* w2  = (const float*)d_in[3];
  const float* b2v = (const float*)d_in[4];
  const float* W   = (const float*)d_in[5];
  float* out = (float*)d_out;

  char* ws = (char*)d_ws;
  float* u     = (float*)(ws + OFF_U);      // raw h2 (squash folded into readers)
  short* w2b   = (short*)(ws + OFF_A);
  short* w1t   = (short*)(ws + OFF_W1T);
  float* Wt    = (float*)(ws + OFF_WT);
  float* spart = (float*)(ws + OFF_SPART);
  float* vsum  = (float*)(ws + OFF_VSUM);

  prep_kernel<<<7040, 256, 0, stream>>>(w2, w2b, w1, w1t, W, Wt);
  conv_fused_kernel<<<512, 256, 0, stream>>>(x, w1t, b1v, w2b, b2v, u);

  // iter 0: uniform c -> s0; vsum = v0
  s_part_kernel<<<dim3(32, 16), 256, 0, stream>>>(u, Wt, nullptr, spart);
  squash_v_kernel<<<20, 256, 0, stream>>>(spart, vsum, 0.1f, 0);
  // iter 1: c from vsum(=v0) in-kernel -> s1; vsum += v1
  s_part_kernel<<<dim3(32, 16), 256, 0, stream>>>(u, Wt, vsum, spart);
  squash_v_kernel<<<20, 256, 0, stream>>>(spart, vsum, 1.0f, 1);
  // iter 2: c from vsum(=v0+v1) -> s2 -> out
  s_part_kernel<<<dim3(32, 16), 256, 0, stream>>>(u, Wt, vsum, spart);
  squash_v_kernel<<<20, 256, 0, stream>>>(spart, out, 1.0f, 0);
}

// Round 9
// 867.976 us; speedup vs baseline: 1.2804x; 1.2804x over previous
//
#include <hip/hip_runtime.h>
#include <math.h>

typedef short short8v __attribute__((ext_vector_type(8)));
typedef float float4v __attribute__((ext_vector_type(4)));

// ---------------- workspace layout (bytes) ----------------
#define OFF_U     ((size_t)0)          // raw h2 (bias included, pre-squash): 512*1152*8*4 = 18,874,368
#define OFF_A     ((size_t)18874368)   // w2b bf16 10,616,832
#define OFF_W1T   ((size_t)29491200)   // w1t bf16 131,072
#define OFF_WT    ((size_t)30670848)   // Wtb bf16 [n][o][e][d]: 2,949,120
#define OFF_SPART ((size_t)33619968)   // [16][512][160] f32 = 5,242,880
#define OFF_VSUM  ((size_t)38862848)   // 327,680 (end 39,190,528)

__device__ inline short f2bf(float f) {
  union { float f; unsigned u; } v; v.f = f;
  unsigned r = v.u + 0x7FFFu + ((v.u >> 16) & 1u);
  return (short)(r >> 16);
}
__device__ inline float bf2f(short s) {
  union { unsigned u; float f; } v; v.u = ((unsigned)(unsigned short)s) << 16;
  return v.f;
}

// ---------------- merged prep: w2b | w1t | Wtb ----------------
// grid 7040: [0,1024) transpose w2->w2b, [1024,1280) w1->w1t, [1280,7040) W->Wtb
__global__ __launch_bounds__(256) void prep_kernel(
    const float* __restrict__ w2, short* __restrict__ w2b,
    const float* __restrict__ w1, short* __restrict__ w1t,
    const float* __restrict__ W, short* __restrict__ Wtb) {
  __shared__ short tl[81][66];
  int bx = blockIdx.x, t = threadIdx.x;
  if (bx < 1024) {
    int co = bx >> 2, ci0 = (bx & 3) * 64;
    for (int f = t; f < 64 * 81; f += 256) {
      int cip = f / 81, tap = f % 81;
      tl[tap][cip] = f2bf(w2[((size_t)co * 256 + ci0 + cip) * 81 + tap]);
    }
    __syncthreads();
    for (int f = t; f < 81 * 64; f += 256) {
      int tap = f >> 6, cip = f & 63;
      w2b[((size_t)tap * 256 + co) * 256 + ci0 + cip] = tl[tap][cip];
    }
  } else if (bx < 1280) {
    int co = bx - 1024;
    w1t[co * 256 + t] = (t < 243) ? f2bf(w1[(size_t)co * 243 + t]) : (short)0;
  } else {
    int idx = (bx - 1280) * 256 + t;
    if (idx < 1152 * 1280) {
      int n = idx / 1280, r = idx - n * 1280;
      int o = r >> 7, de = r & 127;
      int d = de >> 4, e = de & 15;
      Wtb[(((size_t)n * 10 + o) * 16 + e) * 8 + d] = f2bf(W[idx]);
    }
  }
}

// ---------------- fused conv1(MFMA)+relu+conv2(MFMA) -> h2 raw ----------------
// grid (256 batch-pairs, 2 co-halves), 256 threads (4 waves), 2 blocks/CU.
// Per ci-chunk of 32:
//   conv1: M=400 pos x N=32 co x K=256(pad 243), A gathered from x-LDS, B=w1t global
//          (computed once per co-half: 2x redundant, cheap)
//   conv2: 81-tap implicit GEMM, M=80 (2b x 40pad), N=128 (this co-half), B=w2b global
__global__ __launch_bounds__(256, 2) void conv_fused_kernel(
    const float* __restrict__ x, const short* __restrict__ w1t,
    const float* __restrict__ b1v, const short* __restrict__ w2b,
    const float* __restrict__ b2v, float* __restrict__ h2) {
  __shared__ short xsb[4704];        // 2 batches of x, bf16 (9.4 KB)
  __shared__ short h1l[800][40];     // h1 chunk bf16 [bb*400+pos][32ci pad40] (64 KB)

  int b0 = blockIdx.x * 2;
  int coh = blockIdx.y;              // co-half: this block computes co in [coh*128, coh*128+128)
  int t = threadIdx.x;
  int lane = t & 63;
  int wv = t >> 6;
  int l15 = lane & 15, lq = lane >> 4;

  for (int i = t; i < 4704; i += 256) xsb[i] = f2bf(x[(size_t)b0 * 2352 + i]);

  float4v acc2[5][2];
#pragma unroll
  for (int mt = 0; mt < 5; mt++)
#pragma unroll
    for (int nt = 0; nt < 2; nt++) acc2[mt][nt] = (float4v){0.f, 0.f, 0.f, 0.f};

  int rowb[5];
#pragma unroll
  for (int mt = 0; mt < 5; mt++) {
    int m = mt * 16 + l15;
    int ab = (m >= 40) ? 1 : 0;
    int s = m - 40 * ab;
    if (s >= 36) s = 0;               // pad rows read row 0; discarded at store
    int sx = (s * 43) >> 8;           // s/6
    int sy = s - 6 * sx;
    rowb[mt] = ab * 400 + sx * 40 + sy * 2;   // h1l row = rowb + kx*20 + ky
  }
  int co[2];
#pragma unroll
  for (int nt = 0; nt < 2; nt++) co[nt] = coh * 128 + wv * 32 + nt * 16 + l15;

  int nmt = (wv == 0) ? 7 : 6;        // 25 conv1 M-tiles split 7/6/6/6
  int px1[7], py1[7];
#pragma unroll
  for (int j = 0; j < 7; j++) {
    int pos = (wv + 4 * j) * 16 + l15;
    if (pos >= 400) pos = 0;
    px1[j] = (pos * 3277) >> 16;      // pos/20
    py1[j] = pos - 20 * px1[j];
  }

  for (int ch = 0; ch < 8; ch++) {
    int ci0 = ch * 32;
    __syncthreads();   // prev conv2 done with h1l (also covers xsb staging)

    // ======== conv1 phase (MFMA), per batch ========
    for (int bb = 0; bb < 2; bb++) {
      const short* xb = &xsb[bb * 2352];
      float4v acc1[7][2];
#pragma unroll
      for (int j = 0; j < 7; j++)
#pragma unroll
        for (int nt = 0; nt < 2; nt++) acc1[j][nt] = (float4v){0.f, 0.f, 0.f, 0.f};
#pragma unroll 1
      for (int kk = 0; kk < 8; kk++) {
        int k0 = kk * 32 + lq * 8;
        int cin = (k0 * 810) >> 16;            // k0/81
        int rem = k0 - 81 * cin;
        int kx = (rem * 57) >> 9;              // rem/9
        int ky = rem - 9 * kx;
        int nv = 243 - k0; if (nv > 8) nv = 8; if (nv < 0) nv = 0;
        int n1 = 9 - ky; if (n1 > 8) n1 = 8;
        int d2 = (kx < 8) ? (28 - ky) : (560 - ky);
        short8v b1f[2];
#pragma unroll
        for (int nt = 0; nt < 2; nt++)
          b1f[nt] = *(const short8v*)(w1t + (size_t)(ci0 + nt * 16 + l15) * 256 + k0);
#pragma unroll
        for (int j = 0; j < 7; j++) {
          if (j < nmt) {
            int o1 = cin * 784 + (px1[j] + kx) * 28 + py1[j] + ky;
            short8v a;
#pragma unroll
            for (int jj = 0; jj < 8; jj++) {
              int idx = (jj < n1) ? (o1 + jj) : (o1 + d2 + jj - n1);
              if (jj >= nv) idx = 0;
              short vsh = xb[idx];
              a[jj] = (jj < nv) ? vsh : (short)0;
            }
#pragma unroll
            for (int nt = 0; nt < 2; nt++)
              acc1[j][nt] = __builtin_amdgcn_mfma_f32_16x16x32_bf16(
                  a, b1f[nt], acc1[j][nt], 0, 0, 0);
          }
        }
      }
      float bs[2];
#pragma unroll
      for (int nt = 0; nt < 2; nt++) bs[nt] = b1v[ci0 + nt * 16 + l15];
#pragma unroll
      for (int j = 0; j < 7; j++) {
        if (j < nmt) {
#pragma unroll
          for (int nt = 0; nt < 2; nt++) {
#pragma unroll
            for (int r = 0; r < 4; r++) {
              int pos = (wv + 4 * j) * 16 + lq * 4 + r;
              float h = acc1[j][nt][r] + bs[nt];
              h1l[bb * 400 + pos][nt * 16 + l15] = f2bf(h > 0.f ? h : 0.f);
            }
          }
        }
      }
    }
    __syncthreads();   // h1l ready

    // ======== conv2 phase: 81 taps, K=32, B-prefetch ring depth 3 ========
    short8v bA[2], bB[2], bC[2];
#pragma unroll
    for (int nt = 0; nt < 2; nt++) {
      const short* wb = w2b + (size_t)co[nt] * 256 + ci0 + lq * 8;
      bA[nt] = *(const short8v*)(wb);
      bB[nt] = *(const short8v*)(wb + 65536);
      bC[nt] = *(const short8v*)(wb + 2 * 65536);
    }
#pragma unroll 1
    for (int tg = 0; tg < 27; tg++) {
#pragma unroll
      for (int sl = 0; sl < 3; sl++) {
        int tap = tg * 3 + sl;
        int kx = (tap * 57) >> 9;
        int ky = tap - 9 * kx;
        int tf = tap + 3; if (tf > 80) tf = 80;
        short8v bcur[2];
#pragma unroll
        for (int nt = 0; nt < 2; nt++)
          bcur[nt] = (sl == 0) ? bA[nt] : (sl == 1) ? bB[nt] : bC[nt];
#pragma unroll
        for (int nt = 0; nt < 2; nt++) {
          short8v bn = *(const short8v*)(w2b + (size_t)tf * 65536 +
                                         (size_t)co[nt] * 256 + ci0 + lq * 8);
          if (sl == 0) bA[nt] = bn; else if (sl == 1) bB[nt] = bn; else bC[nt] = bn;
        }
        int dly = kx * 20 + ky;
#pragma unroll
        for (int mt = 0; mt < 5; mt++) {
          short8v af = *(const short8v*)&h1l[rowb[mt] + dly][lq * 8];
#pragma unroll
          for (int nt = 0; nt < 2; nt++)
            acc2[mt][nt] = __builtin_amdgcn_mfma_f32_16x16x32_bf16(
                af, bcur[nt], acc2[mt][nt], 0, 0, 0);
        }
      }
    }
  }

  // ---- epilogue: bias + store raw h2[b][co][s] (squash folded into readers) ----
#pragma unroll
  for (int nt = 0; nt < 2; nt++) {
    float bias = b2v[co[nt]];
#pragma unroll
    for (int mt = 0; mt < 5; mt++) {
#pragma unroll
      for (int r = 0; r < 4; r++) {
        int m = mt * 16 + lq * 4 + r;
        int ab = (m >= 40) ? 1 : 0;
        int s = m - 40 * ab;
        if (s < 36)
          h2[((size_t)(b0 + ab) * 256 + co[nt]) * 36 + s] = acc2[mt][nt][r] + bias;
      }
    }
  }
}

// ---------------- fused routing pass: squash(u) + logits + softmax + s partials ----------------
// thread=(b,e): bl[o] via shfl_xor reduce over the 16 e-lanes; c in-register.
// vsum==nullptr -> iter 0 (uniform c; spart scaled 0.1 later in squash_v).
__global__ __launch_bounds__(256) void s_part_kernel(
    const float* __restrict__ h2u, const short* __restrict__ Wtb,
    const float* __restrict__ vsum, float* __restrict__ spart) {
  int bt = blockIdx.x, nc = blockIdx.y;
  int t = threadIdx.x;
  int bq = t >> 4, e = t & 15;
  int b = bt * 16 + bq;
  float vsp[10];
  if (vsum != nullptr) {
#pragma unroll
    for (int o = 0; o < 10; o++) vsp[o] = vsum[(size_t)b * 160 + o * 16 + e];
  }
  float acc[10];
#pragma unroll
  for (int o = 0; o < 10; o++) acc[o] = 0.f;
  int n0 = nc * 72;
#pragma unroll 2
  for (int n = n0; n < n0 + 72; n++) {
    const float4* up = (const float4*)(h2u + ((size_t)b * 1152 + n) * 8);
    float4 u0 = up[0], u1 = up[1];
    float sn = u0.x*u0.x + u0.y*u0.y + u0.z*u0.z + u0.w*u0.w +
               u1.x*u1.x + u1.y*u1.y + u1.z*u1.z + u1.w*u1.w;
    float sc = sn / (1.f + sn) / (sqrtf(sn) + 1e-6f);
    u0.x *= sc; u0.y *= sc; u0.z *= sc; u0.w *= sc;
    u1.x *= sc; u1.y *= sc; u1.z *= sc; u1.w *= sc;
    const short8v* wp = (const short8v*)(Wtb + ((size_t)n * 160 + e) * 8);
    float uh[10];
#pragma unroll
    for (int o = 0; o < 10; o++) {
      short8v w = wp[o * 16];          // stride between o's: 16*8 bf16
      uh[o] = u0.x * bf2f(w[0]) + u0.y * bf2f(w[1]) +
              u0.z * bf2f(w[2]) + u0.w * bf2f(w[3]) +
              u1.x * bf2f(w[4]) + u1.y * bf2f(w[5]) +
              u1.z * bf2f(w[6]) + u1.w * bf2f(w[7]);
    }
    if (vsum != nullptr) {
      float bl[10];
#pragma unroll
      for (int o = 0; o < 10; o++) {
        float r = uh[o] * vsp[o];
        r += __shfl_xor(r, 1);
        r += __shfl_xor(r, 2);
        r += __shfl_xor(r, 4);
        r += __shfl_xor(r, 8);
        bl[o] = r;
      }
      float m = bl[0];
#pragma unroll
      for (int o = 1; o < 10; o++) m = fmaxf(m, bl[o]);
      float sum = 0.f;
#pragma unroll
      for (int o = 0; o < 10; o++) { bl[o] = __expf(bl[o] - m); sum += bl[o]; }
      float inv = 1.f / sum;
#pragma unroll
      for (int o = 0; o < 10; o++) acc[o] = fmaf(bl[o] * inv, uh[o], acc[o]);
    } else {
#pragma unroll
      for (int o = 0; o < 10; o++) acc[o] += uh[o];
    }
  }
  float* sp = spart + (size_t)nc * 81920 + (size_t)b * 160 + e;
#pragma unroll
  for (int o = 0; o < 10; o++) sp[o * 16] = acc[o];
}

// ---------------- v = squash(prescale * sum_parts); dst = v or dst += v ----------------
__global__ void squash_v_kernel(const float* __restrict__ spart,
                                float* __restrict__ dst, float prescale,
                                int accumulate) {
  int g = blockIdx.x * 256 + threadIdx.x;
  if (g >= 5120) return;
  float r[16];
#pragma unroll
  for (int e = 0; e < 16; e++) r[e] = 0.f;
#pragma unroll
  for (int p = 0; p < 16; p++) {
    const float4* sp = (const float4*)(spart + (size_t)p * 81920 + (size_t)g * 16);
#pragma unroll
    for (int q = 0; q < 4; q++) {
      float4 f4 = sp[q];
      r[4 * q] += f4.x; r[4 * q + 1] += f4.y; r[4 * q + 2] += f4.z; r[4 * q + 3] += f4.w;
    }
  }
  float sn = 0.f;
#pragma unroll
  for (int e = 0; e < 16; e++) { r[e] *= prescale; sn += r[e] * r[e]; }
  float scale = sn / (1.f + sn) / (sqrtf(sn) + 1e-6f);
  float* q = dst + (size_t)g * 16;
#pragma unroll
  for (int e = 0; e < 16; e++) {
    float val = r[e] * scale;
    q[e] = accumulate ? (q[e] + val) : val;
  }
}

extern "C" void kernel_launch(void* const* d_in, const int* in_sizes, int n_in,
                              void* d_out, int out_size, void* d_ws, size_t ws_size,
                              hipStream_t stream) {
  const float* x   = (const float*)d_in[0];
  const float* w1  = (const float*)d_in[1];
  const float* b1v = (const float*)d_in[2];
  const float* w2  = (const float*)d_in[3];
  const float* b2v = (const float*)d_in[4];
  const float* W   = (const float*)d_in[5];
  float* out = (float*)d_out;

  char* ws = (char*)d_ws;
  float* u     = (float*)(ws + OFF_U);      // raw h2 (squash folded into readers)
  short* w2b   = (short*)(ws + OFF_A);
  short* w1t   = (short*)(ws + OFF_W1T);
  short* Wtb   = (short*)(ws + OFF_WT);
  float* spart = (float*)(ws + OFF_SPART);
  float* vsum  = (float*)(ws + OFF_VSUM);

  prep_kernel<<<7040, 256, 0, stream>>>(w2, w2b, w1, w1t, W, Wtb);
  conv_fused_kernel<<<dim3(256, 2), 256, 0, stream>>>(x, w1t, b1v, w2b, b2v, u);

  // iter 0: uniform c -> s0; vsum = v0
  s_part_kernel<<<dim3(32, 16), 256, 0, stream>>>(u, Wtb, nullptr, spart);
  squash_v_kernel<<<20, 256, 0, stream>>>(spart, vsum, 0.1f, 0);
  // iter 1: c from vsum(=v0) in-kernel -> s1; vsum += v1
  s_part_kernel<<<dim3(32, 16), 256, 0, stream>>>(u, Wtb, vsum, spart);
  squash_v_kernel<<<20, 256, 0, stream>>>(spart, vsum, 1.0f, 1);
  // iter 2: c from vsum(=v0+v1) -> s2 -> out
  s_part_kernel<<<dim3(32, 16), 256, 0, stream>>>(u, Wtb, vsum, spart);
  squash_v_kernel<<<20, 256, 0, stream>>>(spart, out, 1.0f, 0);
}

// Round 10
// 856.852 us; speedup vs baseline: 1.2970x; 1.0130x over previous
//
#include <hip/hip_runtime.h>
#include <math.h>

typedef short short4v __attribute__((ext_vector_type(4)));
typedef short short8v __attribute__((ext_vector_type(8)));
typedef float float4v __attribute__((ext_vector_type(4)));
typedef unsigned uint4v __attribute__((ext_vector_type(4)));

// ---------------- workspace layout (bytes) ----------------
#define OFF_U     ((size_t)0)          // raw h2 (bias included, pre-squash): 512*1152*8*4 = 18,874,368
#define OFF_A     ((size_t)18874368)   // w2b bf16 10,616,832
#define OFF_W1T   ((size_t)29491200)   // w1t bf16 256*448*2 = 229,376 (gap to OFF_WT is 1.18MB, fits)
#define OFF_WT    ((size_t)30670848)   // Wtb bf16 [n][o][e][d]: 2,949,120
#define OFF_SPART ((size_t)33619968)   // [16][512][160] f32 = 5,242,880
#define OFF_VSUM  ((size_t)38862848)   // 327,680 (end 39,190,528)

__device__ inline short f2bf(float f) {
  union { float f; unsigned u; } v; v.f = f;
  unsigned r = v.u + 0x7FFFu + ((v.u >> 16) & 1u);
  return (short)(r >> 16);
}
__device__ inline float bf2f(short s) {
  union { unsigned u; float f; } v; v.u = ((unsigned)(unsigned short)s) << 16;
  return v.f;
}

// ---------------- merged prep: w2b | w1t(ky-16-padded) | Wtb ----------------
// grid 7040: [0,1024) w2->w2b, [1024,1280) w1->w1t K=448, [1280,7040) W->Wtb
__global__ __launch_bounds__(256) void prep_kernel(
    const float* __restrict__ w2, short* __restrict__ w2b,
    const float* __restrict__ w1, short* __restrict__ w1t,
    const float* __restrict__ W, short* __restrict__ Wtb) {
  __shared__ short tl[81][66];
  int bx = blockIdx.x, t = threadIdx.x;
  if (bx < 1024) {
    int co = bx >> 2, ci0 = (bx & 3) * 64;
    for (int f = t; f < 64 * 81; f += 256) {
      int cip = f / 81, tap = f % 81;
      tl[tap][cip] = f2bf(w2[((size_t)co * 256 + ci0 + cip) * 81 + tap]);
    }
    __syncthreads();
    for (int f = t; f < 81 * 64; f += 256) {
      int tap = f >> 6, cip = f & 63;
      w2b[((size_t)tap * 256 + co) * 256 + ci0 + cip] = tl[tap][cip];
    }
  } else if (bx < 1280) {
    int co = bx - 1024;
    for (int kp = t; kp < 448; kp += 256) {
      short v = 0;
      if (kp < 432) {
        int cin = kp / 144, r = kp - cin * 144;
        int kx = r >> 4, ky = r & 15;
        if (ky < 9) v = f2bf(w1[(size_t)co * 243 + cin * 81 + kx * 9 + ky]);
      }
      w1t[co * 448 + kp] = v;
    }
  } else {
    int idx = (bx - 1280) * 256 + t;
    if (idx < 1152 * 1280) {
      int n = idx / 1280, r = idx - n * 1280;
      int o = r >> 7, de = r & 127;
      int d = de >> 4, e = de & 15;
      Wtb[(((size_t)n * 10 + o) * 16 + e) * 8 + d] = f2bf(W[idx]);
    }
  }
}

// ---------------- fused conv1(MFMA)+relu+conv2(MFMA) -> h2 raw ----------------
// grid (256 batch-pairs, 2 co-halves), 256 threads (4 waves), 2 blocks/CU.
// conv1 K-layout padded: k' = cin*144 + kx*16 + ky (K=448); pad-k weights are ZERO,
// so A-frags are 8 CONTIGUOUS shorts of x (garbage at pad positions is multiplied by 0).
// Parity-duplicated x in LDS makes every frag 4 aligned b32 reads, no masking.
__global__ __launch_bounds__(256, 2) void conv_fused_kernel(
    const float* __restrict__ x, const short* __restrict__ w1t,
    const float* __restrict__ b1v, const short* __restrict__ w2b,
    const float* __restrict__ b2v, float* __restrict__ h2) {
  __shared__ short xs2[2][2][2360];  // [copy][batch][idx]; copy1[i] = x[i+1] (18.9 KB)
  __shared__ short h1l[800][36];     // h1 chunk bf16 [bb*400+pos][32ci pad36] (57.6 KB)

  int b0 = blockIdx.x * 2;
  int coh = blockIdx.y;
  int t = threadIdx.x;
  int lane = t & 63;
  int wv = t >> 6;
  int l15 = lane & 15, lq = lane >> 4;

  // zero-fill the tail pads of both copies (disjoint from value writes below)
  if (t < 64) {
    int c = t & 1, bb2 = (t >> 1) & 1, k = t >> 2;   // k 0..15
    int idx = 2351 + k;
    if (idx < 2360 && (c == 1 || idx >= 2352)) xs2[c][bb2][idx] = 0;
  }
  for (int i = t; i < 4704; i += 256) {
    int bb = i / 2352, j = i - bb * 2352;
    short v = f2bf(x[(size_t)b0 * 2352 + i]);
    xs2[0][bb][j] = v;
    if (j >= 1) xs2[1][bb][j - 1] = v;
  }

  float4v acc2[5][2];
#pragma unroll
  for (int mt = 0; mt < 5; mt++)
#pragma unroll
    for (int nt = 0; nt < 2; nt++) acc2[mt][nt] = (float4v){0.f, 0.f, 0.f, 0.f};

  int rowb[5];
#pragma unroll
  for (int mt = 0; mt < 5; mt++) {
    int m = mt * 16 + l15;
    int ab = (m >= 40) ? 1 : 0;
    int s = m - 40 * ab;
    if (s >= 36) s = 0;               // pad rows read row 0; discarded at store
    int sx = (s * 43) >> 8;           // s/6
    int sy = s - 6 * sx;
    rowb[mt] = ab * 400 + sx * 40 + sy * 2;   // h1l row = rowb + kx*20 + ky
  }
  int co[2];
#pragma unroll
  for (int nt = 0; nt < 2; nt++) co[nt] = coh * 128 + wv * 32 + nt * 16 + l15;

  int nmt = (wv == 0) ? 7 : 6;        // 25 conv1 M-tiles split 7/6/6/6
  int px1[7], py1[7];
#pragma unroll
  for (int j = 0; j < 7; j++) {
    int pos = (wv + 4 * j) * 16 + l15;
    if (pos >= 400) pos = 0;
    px1[j] = (pos * 3277) >> 16;      // pos/20
    py1[j] = pos - 20 * px1[j];
  }

  for (int ch = 0; ch < 8; ch++) {
    int ci0 = ch * 32;
    __syncthreads();   // prev conv2 done with h1l (also covers xs2 staging)

    // ======== conv1 phase (MFMA), per batch; K=448 in 14 steps ========
    for (int bb = 0; bb < 2; bb++) {
      float4v acc1[7][2];
#pragma unroll
      for (int j = 0; j < 7; j++)
#pragma unroll
        for (int nt = 0; nt < 2; nt++) acc1[j][nt] = (float4v){0.f, 0.f, 0.f, 0.f};
#pragma unroll 1
      for (int kk = 0; kk < 14; kk++) {
        int k0 = kk * 32 + lq * 8;
        int cin = (k0 >= 288) ? 2 : ((k0 >= 144) ? 1 : 0);
        int r = k0 - cin * 144;
        int kx = r >> 4;
        int kyb = r & 15;              // 0 or 8
        short8v b1f[2];
#pragma unroll
        for (int nt = 0; nt < 2; nt++)
          b1f[nt] = *(const short8v*)(w1t + (size_t)(ci0 + nt * 16 + l15) * 448 + k0);
#pragma unroll
        for (int j = 0; j < 7; j++) {
          if (j < nmt) {
            int o1 = cin * 784 + (px1[j] + kx) * 28 + py1[j] + kyb;
            if (k0 >= 432) o1 = 0;     // dead frag (zero weights); keep LDS in-bounds
            int p = o1 & 1;
            const unsigned* q = (const unsigned*)&xs2[p][bb][o1 - p];
            uint4v w4 = {q[0], q[1], q[2], q[3]};
            short8v a = __builtin_bit_cast(short8v, w4);
#pragma unroll
            for (int nt = 0; nt < 2; nt++)
              acc1[j][nt] = __builtin_amdgcn_mfma_f32_16x16x32_bf16(
                  a, b1f[nt], acc1[j][nt], 0, 0, 0);
          }
        }
      }
      float bs[2];
#pragma unroll
      for (int nt = 0; nt < 2; nt++) bs[nt] = b1v[ci0 + nt * 16 + l15];
#pragma unroll
      for (int j = 0; j < 7; j++) {
        if (j < nmt) {
#pragma unroll
          for (int nt = 0; nt < 2; nt++) {
#pragma unroll
            for (int r = 0; r < 4; r++) {
              int pos = (wv + 4 * j) * 16 + lq * 4 + r;
              float h = acc1[j][nt][r] + bs[nt];
              h1l[bb * 400 + pos][nt * 16 + l15] = f2bf(h > 0.f ? h : 0.f);
            }
          }
        }
      }
    }
    __syncthreads();   // h1l ready

    // ======== conv2 phase: 81 taps, K=32, B-prefetch ring depth 3 ========
    short8v bA[2], bB[2], bC[2];
#pragma unroll
    for (int nt = 0; nt < 2; nt++) {
      const short* wb = w2b + (size_t)co[nt] * 256 + ci0 + lq * 8;
      bA[nt] = *(const short8v*)(wb);
      bB[nt] = *(const short8v*)(wb + 65536);
      bC[nt] = *(const short8v*)(wb + 2 * 65536);
    }
#pragma unroll 1
    for (int tg = 0; tg < 27; tg++) {
#pragma unroll
      for (int sl = 0; sl < 3; sl++) {
        int tap = tg * 3 + sl;
        int kx = (tap * 57) >> 9;
        int ky = tap - 9 * kx;
        int tf = tap + 3; if (tf > 80) tf = 80;
        short8v bcur[2];
#pragma unroll
        for (int nt = 0; nt < 2; nt++)
          bcur[nt] = (sl == 0) ? bA[nt] : (sl == 1) ? bB[nt] : bC[nt];
#pragma unroll
        for (int nt = 0; nt < 2; nt++) {
          short8v bn = *(const short8v*)(w2b + (size_t)tf * 65536 +
                                         (size_t)co[nt] * 256 + ci0 + lq * 8);
          if (sl == 0) bA[nt] = bn; else if (sl == 1) bB[nt] = bn; else bC[nt] = bn;
        }
        int dly = kx * 20 + ky;
#pragma unroll
        for (int mt = 0; mt < 5; mt++) {
          const short4v* ap = (const short4v*)&h1l[rowb[mt] + dly][lq * 8];
          short8v af = __builtin_shufflevector(ap[0], ap[1], 0, 1, 2, 3, 4, 5, 6, 7);
#pragma unroll
          for (int nt = 0; nt < 2; nt++)
            acc2[mt][nt] = __builtin_amdgcn_mfma_f32_16x16x32_bf16(
                af, bcur[nt], acc2[mt][nt], 0, 0, 0);
        }
      }
    }
  }

  // ---- epilogue: bias + store raw h2[b][co][s] (squash folded into readers) ----
#pragma unroll
  for (int nt = 0; nt < 2; nt++) {
    float bias = b2v[co[nt]];
#pragma unroll
    for (int mt = 0; mt < 5; mt++) {
#pragma unroll
      for (int r = 0; r < 4; r++) {
        int m = mt * 16 + lq * 4 + r;
        int ab = (m >= 40) ? 1 : 0;
        int s = m - 40 * ab;
        if (s < 36)
          h2[((size_t)(b0 + ab) * 256 + co[nt]) * 36 + s] = acc2[mt][nt][r] + bias;
      }
    }
  }
}

// ---------------- fused routing pass: squash(u) + logits + softmax + s partials ----------------
// thread=(b,e): bl[o] via shfl_xor reduce over the 16 e-lanes; c in-register.
// vsum==nullptr -> iter 0 (uniform c; spart scaled 0.1 later in squash_v).
__global__ __launch_bounds__(256) void s_part_kernel(
    const float* __restrict__ h2u, const short* __restrict__ Wtb,
    const float* __restrict__ vsum, float* __restrict__ spart) {
  int bt = blockIdx.x, nc = blockIdx.y;
  int t = threadIdx.x;
  int bq = t >> 4, e = t & 15;
  int b = bt * 16 + bq;
  float vsp[10];
  if (vsum != nullptr) {
#pragma unroll
    for (int o = 0; o < 10; o++) vsp[o] = vsum[(size_t)b * 160 + o * 16 + e];
  }
  float acc[10];
#pragma unroll
  for (int o = 0; o < 10; o++) acc[o] = 0.f;
  int n0 = nc * 72;
#pragma unroll 2
  for (int n = n0; n < n0 + 72; n++) {
    const float4* up = (const float4*)(h2u + ((size_t)b * 1152 + n) * 8);
    float4 u0 = up[0], u1 = up[1];
    float sn = u0.x*u0.x + u0.y*u0.y + u0.z*u0.z + u0.w*u0.w +
               u1.x*u1.x + u1.y*u1.y + u1.z*u1.z + u1.w*u1.w;
    float sc = sn / (1.f + sn) / (sqrtf(sn) + 1e-6f);
    u0.x *= sc; u0.y *= sc; u0.z *= sc; u0.w *= sc;
    u1.x *= sc; u1.y *= sc; u1.z *= sc; u1.w *= sc;
    const short8v* wp = (const short8v*)(Wtb + ((size_t)n * 160 + e) * 8);
    float uh[10];
#pragma unroll
    for (int o = 0; o < 10; o++) {
      short8v w = wp[o * 16];
      uh[o] = u0.x * bf2f(w[0]) + u0.y * bf2f(w[1]) +
              u0.z * bf2f(w[2]) + u0.w * bf2f(w[3]) +
              u1.x * bf2f(w[4]) + u1.y * bf2f(w[5]) +
              u1.z * bf2f(w[6]) + u1.w * bf2f(w[7]);
    }
    if (vsum != nullptr) {
      float bl[10];
#pragma unroll
      for (int o = 0; o < 10; o++) {
        float r = uh[o] * vsp[o];
        r += __shfl_xor(r, 1);
        r += __shfl_xor(r, 2);
        r += __shfl_xor(r, 4);
        r += __shfl_xor(r, 8);
        bl[o] = r;
      }
      float m = bl[0];
#pragma unroll
      for (int o = 1; o < 10; o++) m = fmaxf(m, bl[o]);
      float sum = 0.f;
#pragma unroll
      for (int o = 0; o < 10; o++) { bl[o] = __expf(bl[o] - m); sum += bl[o]; }
      float inv = 1.f / sum;
#pragma unroll
      for (int o = 0; o < 10; o++) acc[o] = fmaf(bl[o] * inv, uh[o], acc[o]);
    } else {
#pragma unroll
      for (int o = 0; o < 10; o++) acc[o] += uh[o];
    }
  }
  float* sp = spart + (size_t)nc * 81920 + (size_t)b * 160 + e;
#pragma unroll
  for (int o = 0; o < 10; o++) sp[o * 16] = acc[o];
}

// ---------------- v = squash(prescale * sum_parts); dst = v or dst += v ----------------
__global__ void squash_v_kernel(const float* __restrict__ spart,
                                float* __restrict__ dst, float prescale,
                                int accumulate) {
  int g = blockIdx.x * 256 + threadIdx.x;
  if (g >= 5120) return;
  float r[16];
#pragma unroll
  for (int e = 0; e < 16; e++) r[e] = 0.f;
#pragma unroll
  for (int p = 0; p < 16; p++) {
    const float4* sp = (const float4*)(spart + (size_t)p * 81920 + (size_t)g * 16);
#pragma unroll
    for (int q = 0; q < 4; q++) {
      float4 f4 = sp[q];
      r[4 * q] += f4.x; r[4 * q + 1] += f4.y; r[4 * q + 2] += f4.z; r[4 * q + 3] += f4.w;
    }
  }
  float sn = 0.f;
#pragma unroll
  for (int e = 0; e < 16; e++) { r[e] *= prescale; sn += r[e] * r[e]; }
  float scale = sn / (1.f + sn) / (sqrtf(sn) + 1e-6f);
  float* q = dst + (size_t)g * 16;
#pragma unroll
  for (int e = 0; e < 16; e++) {
    float val = r[e] * scale;
    q[e] = accumulate ? (q[e] + val) : val;
  }
}

extern "C" void kernel_launch(void* const* d_in, const int* in_sizes, int n_in,
                              void* d_out, int out_size, void* d_ws, size_t ws_size,
                              hipStream_t stream) {
  const float* x   = (const float*)d_in[0];
  const float* w1  = (const float*)d_in[1];
  const float* b1v = (const float*)d_in[2];
  const float* w2  = (const float*)d_in[3];
  const float* b2v = (const float*)d_in[4];
  const float* W   = (const float*)d_in[5];
  float* out = (float*)d_out;

  char* ws = (char*)d_ws;
  float* u     = (float*)(ws + OFF_U);      // raw h2 (squash folded into readers)
  short* w2b   = (short*)(ws + OFF_A);
  short* w1t   = (short*)(ws + OFF_W1T);
  short* Wtb   = (short*)(ws + OFF_WT);
  float* spart = (float*)(ws + OFF_SPART);
  float* vsum  = (float*)(ws + OFF_VSUM);

  prep_kernel<<<7040, 256, 0, stream>>>(w2, w2b, w1, w1t, W, Wtb);
  conv_fused_kernel<<<dim3(256, 2), 256, 0, stream>>>(x, w1t, b1v, w2b, b2v, u);

  // iter 0: uniform c -> s0; vsum = v0
  s_part_kernel<<<dim3(32, 16), 256, 0, stream>>>(u, Wtb, nullptr, spart);
  squash_v_kernel<<<20, 256, 0, stream>>>(spart, vsum, 0.1f, 0);
  // iter 1: c from vsum(=v0) in-kernel -> s1; vsum += v1
  s_part_kernel<<<dim3(32, 16), 256, 0, stream>>>(u, Wtb, vsum, spart);
  squash_v_kernel<<<20, 256, 0, stream>>>(spart, vsum, 1.0f, 1);
  // iter 2: c from vsum(=v0+v1) -> s2 -> out
  s_part_kernel<<<dim3(32, 16), 256, 0, stream>>>(u, Wtb, vsum, spart);
  squash_v_kernel<<<20, 256, 0, stream>>>(spart, out, 1.0f, 0);
}